// Round 7
// baseline (1096.218 us; speedup 1.0000x reference)
//
#include <hip/hip_runtime.h>
#include <hip/hip_bf16.h>

// Problem dims
static const int kB = 128, kN = 49, kC = 2048, kD = 512, kE = 512, kV = 10000, kT = 20;

typedef __bf16 bf16x8 __attribute__((ext_vector_type(8)));
typedef float  f32x4v __attribute__((ext_vector_type(4)));
typedef float  f32x2v __attribute__((ext_vector_type(2)));
typedef _Float16 h8_t __attribute__((ext_vector_type(8)));
typedef unsigned short u16;
typedef unsigned int u32;
typedef unsigned char u8;

#if defined(__has_builtin)
#if __has_builtin(__builtin_amdgcn_cvt_pk_f32_fp8) && __has_builtin(__builtin_amdgcn_cvt_pk_fp8_f32)
#define HAS_FP8CVT 1
#endif
#endif
#ifndef HAS_FP8CVT
#define HAS_FP8CVT 0
#endif

#define AS1 __attribute__((address_space(1)))
#define AS3 __attribute__((address_space(3)))

__device__ __forceinline__ float sigmoidf_(float x){ return 1.f/(1.f+expf(-x)); }
__device__ __forceinline__ u16 f2b(float x){ __hip_bfloat16 h = __float2bfloat16(x); return *(u16*)&h; }
__device__ __forceinline__ float bu2f(u32 u){ u32 w = u << 16; union{u32 u; float f;} c; c.u = w; return c.f; }

#if !HAS_FP8CVT
// scalar fallbacks (correctness path only)
__device__ __forceinline__ float dec_fp8(u8 b){
    int s = b >> 7, e = (b >> 3) & 15, m = b & 7;
    float v = e ? ldexpf(1.f + m*0.125f, e - 7) : ldexpf(m*0.125f, -6);
    return s ? -v : v;
}
__device__ __forceinline__ u8 enc_fp8(float v){
    u8 s = (v < 0.f) ? 0x80 : 0;
    float a = fabsf(v);
    if (!(a > 0.f)) return 0;
    a = fminf(a, 448.f);
    int e; float fr = frexpf(a, &e);      // a = fr*2^e, fr in [0.5,1)
    (void)fr;
    int ebits = e - 1 + 7;
    if (ebits < 1){
        float q = rintf(ldexpf(a, 9));
        if (q >= 8.f) return s | 0x08;
        return s | (u8)(int)q;
    }
    float mant = ldexpf(a, -(e - 1));     // [1,2)
    int m = (int)rintf((mant - 1.f)*8.f);
    if (m == 8){ m = 0; ebits++; }
    if (ebits > 15){ ebits = 15; m = 6; }
    return s | (u8)(ebits << 3) | (u8)m;
}
#endif

// fp8x8 dot with f32 h-halves
__device__ __forceinline__ float dot8_fp8(uint2 w, f32x4v ha, f32x4v hb, float c){
#if HAS_FP8CVT
    f32x2v d0 = __builtin_amdgcn_cvt_pk_f32_fp8((int)w.x, false);
    f32x2v d1 = __builtin_amdgcn_cvt_pk_f32_fp8((int)w.x, true);
    f32x2v d2 = __builtin_amdgcn_cvt_pk_f32_fp8((int)w.y, false);
    f32x2v d3 = __builtin_amdgcn_cvt_pk_f32_fp8((int)w.y, true);
    c = fmaf(d0[0], ha[0], c); c = fmaf(d0[1], ha[1], c);
    c = fmaf(d1[0], ha[2], c); c = fmaf(d1[1], ha[3], c);
    c = fmaf(d2[0], hb[0], c); c = fmaf(d2[1], hb[1], c);
    c = fmaf(d3[0], hb[2], c); c = fmaf(d3[1], hb[3], c);
#else
    u8 by[8];
    *(u32*)&by[0] = w.x; *(u32*)&by[4] = w.y;
    c = fmaf(dec_fp8(by[0]), ha[0], c); c = fmaf(dec_fp8(by[1]), ha[1], c);
    c = fmaf(dec_fp8(by[2]), ha[2], c); c = fmaf(dec_fp8(by[3]), ha[3], c);
    c = fmaf(dec_fp8(by[4]), hb[0], c); c = fmaf(dec_fp8(by[5]), hb[1], c);
    c = fmaf(dec_fp8(by[6]), hb[2], c); c = fmaf(dec_fp8(by[7]), hb[3], c);
#endif
    return c;
}

// ================= bf16 MFMA NT GEMM (TBK=64) =================
// C[M,N] = act(A[M,K]@W[N,K]^T + bias + add1[m&a1mask]) [*mul2 for act3], fp32 acc.
// REQUIRES: M % 128 == 0; K % 64 == 0; W has >= ceil(N/128)*128 readable rows.
// swz!=0: 1D grid, XCD-grouped decode (XCD k owns N-tiles == k mod 8).
#define TBM 128
#define TBN 128
#define TBK 64

__global__ __launch_bounds__(256) void gemm_bf16(
    const u16* __restrict__ A, int lda,
    const u16* __restrict__ W, int ldw,
    float* __restrict__ C, u16* __restrict__ Cbf, int ldc,
    int M, int N, int K,
    const float* __restrict__ bias,
    const float* __restrict__ add1, int ld1, int a1mask,
    int act,
    const u16* __restrict__ mul2, int ldm,
    int swz)
{
    __shared__ __align__(16) u16 As[TBM*TBK];
    __shared__ __align__(16) u16 Bs[TBN*TBK];
    const int tid = threadIdx.x;
    int bm, bn;
    if (swz){
        const int mblocks = (M + TBM - 1)/TBM;
        const int per_g = mblocks*8;
        const int id = blockIdx.x;
        const int g = id/per_g, r = id - g*per_g;
        bm = (r >> 3)*TBM;
        bn = (g*8 + (r & 7))*TBN;
        if (bn >= N) return;               // uniform per block, before any barrier
    } else {
        bm = blockIdx.y * TBM;
        bn = blockIdx.x * TBN;
    }
    const int wave = tid >> 6, lane = tid & 63;
    const int wm = (wave >> 1) * 64, wn = (wave & 1) * 64;
    const int lm = lane & 15, quad = lane >> 4;
    f32x4v acc[4][4] = {};
    for (int k0 = 0; k0 < K; k0 += TBK) {
        #pragma unroll
        for (int h = 0; h < 4; ++h) {
            const int slot = h*256 + tid;           // 0..1023
            const int row = slot >> 3, kf = (slot & 7)*8;
            const int wbase = (h*256 + (tid & 192))*8;  // wave-uniform, u16 units
            __builtin_amdgcn_global_load_lds((const AS1 u32*)(A + (size_t)(bm + row)*lda + k0 + kf),
                                             (AS3 u32*)(As + wbase), 16, 0, 0);
            __builtin_amdgcn_global_load_lds((const AS1 u32*)(W + (size_t)(bn + row)*ldw + k0 + kf),
                                             (AS3 u32*)(Bs + wbase), 16, 0, 0);
        }
        __syncthreads();
        #pragma unroll
        for (int sub = 0; sub < 2; ++sub){
            bf16x8 afr[4], bfr[4];
            #pragma unroll
            for (int i = 0; i < 4; ++i) afr[i] = *(const bf16x8*)&As[(wm + i*16 + lm)*TBK + quad*8 + sub*32];
            #pragma unroll
            for (int j = 0; j < 4; ++j) bfr[j] = *(const bf16x8*)&Bs[(wn + j*16 + lm)*TBK + quad*8 + sub*32];
            #pragma unroll
            for (int i = 0; i < 4; ++i)
                #pragma unroll
                for (int j = 0; j < 4; ++j)
                    acc[i][j] = __builtin_amdgcn_mfma_f32_16x16x32_bf16(afr[i], bfr[j], acc[i][j], 0, 0, 0);
        }
        __syncthreads();
    }
    #pragma unroll
    for (int i = 0; i < 4; ++i) {
        int mbase = bm + wm + i*16 + quad*4;
        #pragma unroll
        for (int j = 0; j < 4; ++j) {
            int n = bn + wn + j*16 + lm;
            if (n >= N) continue;
            float bv = bias ? bias[n] : 0.f;
            #pragma unroll
            for (int rr2 = 0; rr2 < 4; ++rr2) {
                int m = mbase + rr2;
                float v = acc[i][j][rr2] + bv;
                if (add1) v += add1[(size_t)(m & a1mask)*ld1 + n];
                if (act == 1) v = fmaxf(v, 0.f);
                else if (act == 2) v = tanhf(v);
                else if (act == 3) v = sigmoidf_(v) * bu2f(mul2[(size_t)m*ldm + n]);
                if (C)   C[(size_t)m*ldc + n] = v;
                if (Cbf) Cbf[(size_t)m*ldc + n] = f2b(v);
            }
        }
    }
}

// ================= fused conversion kernels =================
// img fp32 [B][49][2048] -> bf16 (same layout) AND mean over n -> bf16 [B][2048]
__global__ __launch_bounds__(256) void img_cvt_mean_k(const float* __restrict__ img,
                                                      u16* __restrict__ img_bf,
                                                      u16* __restrict__ meanb){
    int idx = blockIdx.x*256 + threadIdx.x;       // B * C/8 = 32768
    int b = idx >> 8, c8 = idx & 255;
    const float* p = img + (size_t)b*kN*kC + c8*8;
    f32x4v s0 = {0,0,0,0}, s1 = {0,0,0,0};
    for (int n = 0; n < kN; ++n){
        f32x4v f0 = *(const f32x4v*)(p + (size_t)n*kC);
        f32x4v f1 = *(const f32x4v*)(p + (size_t)n*kC + 4);
        s0 += f0; s1 += f1;
        union { u16 u[8]; uint4 v; } pk;
        pk.u[0]=f2b(f0[0]); pk.u[1]=f2b(f0[1]); pk.u[2]=f2b(f0[2]); pk.u[3]=f2b(f0[3]);
        pk.u[4]=f2b(f1[0]); pk.u[5]=f2b(f1[1]); pk.u[6]=f2b(f1[2]); pk.u[7]=f2b(f1[3]);
        *(uint4*)(img_bf + ((size_t)(b*kN + n))*kC + c8*8) = pk.v;
    }
    const float inv = 1.f/(float)kN;
    union { u16 u[8]; uint4 v; } pm;
    pm.u[0]=f2b(s0[0]*inv); pm.u[1]=f2b(s0[1]*inv); pm.u[2]=f2b(s0[2]*inv); pm.u[3]=f2b(s0[3]*inv);
    pm.u[4]=f2b(s1[0]*inv); pm.u[5]=f2b(s1[1]*inv); pm.u[6]=f2b(s1[2]*inv); pm.u[7]=f2b(s1[3]*inv);
    *(uint4*)(meanb + (size_t)b*kC + c8*8) = pm.v;
}

// all bf16 weight conversions in ONE kernel via descriptor table.
struct CvtDesc {
    const float* src;
    unsigned long long dst;
    int src_ld, Kshift, start;
};
struct CvtTab { CvtDesc d[16]; int total; };

__global__ __launch_bounds__(256) void multi_cvt_k(CvtTab tab){
    for (int idx = blockIdx.x*256 + threadIdx.x; idx < tab.total; idx += gridDim.x*256){
        int di = 0;
        #pragma unroll
        for (int i = 1; i < 16; ++i) if (idx >= tab.d[i].start) di = i;
        const CvtDesc D = tab.d[di];
        int rel = idx - D.start;
        int rr = rel >> D.Kshift, kc = rel - (rr << D.Kshift);
        const float* p = D.src + (size_t)rr*D.src_ld + kc*8;
        f32x4v f0 = *(const f32x4v*)p, f1 = *(const f32x4v*)(p+4);
        union { u16 u[8]; uint4 v; } pk;
        pk.u[0]=f2b(f0[0]); pk.u[1]=f2b(f0[1]); pk.u[2]=f2b(f0[2]); pk.u[3]=f2b(f0[3]);
        pk.u[4]=f2b(f1[0]); pk.u[5]=f2b(f1[1]); pk.u[6]=f2b(f1[2]); pk.u[7]=f2b(f1[3]);
        *(uint4*)((u16*)D.dst + (((size_t)rr << D.Kshift) + kc)*8) = pk.v;
    }
}

// Whh fp32 [2048][512] -> fp8 e4m3 interleaved [64][2048][8] + per-row scale
__global__ __launch_bounds__(512) void wrec8_prep_k(const float* __restrict__ Whh,
                                                    u8* __restrict__ W8,
                                                    float* __restrict__ rowscale){
    const int row = (blockIdx.x << 3) + (threadIdx.x >> 6);   // 0..2047, one wave per row
    const int l = threadIdx.x & 63;
    const float* src = Whh + (size_t)row*512 + l*8;
    f32x4v v0 = *(const f32x4v*)src, v1 = *(const f32x4v*)(src + 4);
    float mx = 0.f;
    #pragma unroll
    for (int i = 0; i < 4; ++i){ mx = fmaxf(mx, fabsf(v0[i])); mx = fmaxf(mx, fabsf(v1[i])); }
    #pragma unroll
    for (int o = 32; o > 0; o >>= 1) mx = fmaxf(mx, __shfl_xor(mx, o));
    const float se = (mx > 0.f) ? 448.f/mx : 0.f;
    if (l == 0) rowscale[row] = (mx > 0.f) ? mx/448.f : 0.f;
    u32 lo, hi;
#if HAS_FP8CVT
    lo = (u32)__builtin_amdgcn_cvt_pk_fp8_f32(v0[0]*se, v0[1]*se, 0, false);
    lo = (u32)__builtin_amdgcn_cvt_pk_fp8_f32(v0[2]*se, v0[3]*se, (int)lo, true);
    hi = (u32)__builtin_amdgcn_cvt_pk_fp8_f32(v1[0]*se, v1[1]*se, 0, false);
    hi = (u32)__builtin_amdgcn_cvt_pk_fp8_f32(v1[2]*se, v1[3]*se, (int)hi, true);
#else
    u8 by[8];
    #pragma unroll
    for (int i = 0; i < 4; ++i){ by[i] = enc_fp8(v0[i]*se); by[4+i] = enc_fp8(v1[i]*se); }
    lo = *(u32*)&by[0]; hi = *(u32*)&by[4];
#endif
    *(uint2*)&W8[((size_t)l*2048 + row)*8] = make_uint2(lo, hi);
}

// bias2560 = [bih+bhh (2048); 0 (512)]; bcat3 = [bb|bhi|bmi]
__global__ __launch_bounds__(256) void bias_prep_k(const float* bih, const float* bhh,
                                                   const float* bb, const float* bhi, const float* bmi,
                                                   float* bias2560, float* bcat3){
    int i = blockIdx.x*256 + threadIdx.x;
    if (i < 2048) bias2560[i] = bih[i] + bhh[i];
    else if (i < 2560) bias2560[i] = 0.f;
    else if (i < 4096){
        int j = i - 2560;
        bcat3[j] = (j < 512) ? bb[j] : (j < 1024 ? bhi[j-512] : bmi[j-1024]);
    }
}

// we[t*B+b][e] bf16
__global__ __launch_bounds__(256) void emb_gather_k(const int* __restrict__ target,
                                                    const float* __restrict__ emb,
                                                    u16* __restrict__ we){
    int idx = blockIdx.x*256 + threadIdx.x;       // T*B*E
    int e = idx & (kE-1);
    int rr = idx >> 9;                            // t*B + b
    int b = rr & 127, t = rr >> 7;
    float v = 0.f;
    if (t > 0){ int tok = target[b*kT + (t-1)]; v = emb[(size_t)tok*kE + e]; }
    we[idx] = f2b(v);
}

// hp_bf row block 0 = h0 (bf16) for the gtv GEMM
__global__ __launch_bounds__(256) void initcopy_k(const float* __restrict__ initC,
                                                  u16* __restrict__ hp_bf){
    int idx = blockIdx.x*256 + threadIdx.x;       // 128*512
    int b = idx >> 9, d = idx & 511;
    hp_bf[idx] = f2b(initC[(size_t)b*1536 + 512 + d]);
}

// ================= single-launch LSTM recurrence (fp8 weights, 4 gates) =================
// 128 blocks x 1024 threads: thread = (out in [0,512), kh in {0,1} K-half).
// Weight stream 1.05 MB/step/CU from L2; gtv's 5th gate group deferred to a GEMM.
__global__ __launch_bounds__(1024, 1) void scan_k(
    const float* __restrict__ initC,       // [128][1536] vg|h0|m0 (fp32)
    const float* __restrict__ xall,        // [20][128][2560] gate-major cols 0..2047
    const u8* __restrict__ Wrec8,          // [64][2048][8] fp8 e4m3
    const float* __restrict__ rowscale,    // [2048]
    u16* __restrict__ hp_bf,               // [21*128][512]: row (t+1)*128+b written here
    u16* __restrict__ tm_bf)               // [20*128][512]: tanh(m2)
{
    const int b = blockIdx.x, tid = threadIdx.x;
    const int out = tid & 511, kh = tid >> 9;
    __shared__ __align__(16) float shf[512];
    __shared__ float spart[512][4];

    if (tid < 512) shf[tid] = initC[(size_t)b*1536 + 512 + tid];
    float m_reg = (kh == 0) ? initC[(size_t)b*1536 + 1024 + out] : 0.f;
    const float rs0 = rowscale[out],        rs1 = rowscale[512 + out];
    const float rs2 = rowscale[1024 + out], rs3 = rowscale[1536 + out];
    __syncthreads();

    for (int t = 0; t < kT; ++t){
        float a0=0.f, a1=0.f, a2=0.f, a3=0.f;
        const int kc0 = kh*32;
        #pragma unroll 2
        for (int kc = kc0; kc < kc0 + 32; ++kc){
            const u8* wb = Wrec8 + ((size_t)kc*2048 + out)*8;
            f32x4v ha = *(const f32x4v*)&shf[kc*8];
            f32x4v hb = *(const f32x4v*)&shf[kc*8 + 4];
            uint2 w0 = *(const uint2*)(wb);
            uint2 w1 = *(const uint2*)(wb + 4096);
            uint2 w2 = *(const uint2*)(wb + 8192);
            uint2 w3 = *(const uint2*)(wb + 12288);
            a0 = dot8_fp8(w0, ha, hb, a0);
            a1 = dot8_fp8(w1, ha, hb, a1);
            a2 = dot8_fp8(w2, ha, hb, a2);
            a3 = dot8_fp8(w3, ha, hb, a3);
        }
        __syncthreads();                      // all GEMV reads of shf done
        if (kh == 1){
            spart[out][0]=a0; spart[out][1]=a1; spart[out][2]=a2; spart[out][3]=a3;
        }
        __syncthreads();
        if (kh == 0){
            const float* xrow = xall + ((size_t)t*kB + b)*2560;
            a0 = (a0 + spart[out][0])*rs0 + xrow[out];
            a1 = (a1 + spart[out][1])*rs1 + xrow[out + 512];
            a2 = (a2 + spart[out][2])*rs2 + xrow[out + 1024];
            a3 = (a3 + spart[out][3])*rs3 + xrow[out + 1536];
            float i_g = sigmoidf_(a0), f_g = sigmoidf_(a1);
            float g_g = tanhf(a2),     o_g = sigmoidf_(a3);
            m_reg = f_g*m_reg + i_g*g_g;
            float tm = tanhf(m_reg);
            float h2 = o_g*tm;
            shf[out] = h2;
            hp_bf[((size_t)(t+1)*kB + b)*512 + out] = f2b(h2);
            tm_bf[((size_t)t*kB + b)*512 + out] = f2b(tm);
        }
        __syncthreads();
    }
}

// ================= batched attention kernel (fused gH/sWs GEMVs) =================
// XCD-swizzled: all 20 t-blocks of one batch land on one XCD (Vf/zbase L2-hot).
__global__ __launch_bounds__(256) void attn_k(
    const float* __restrict__ H_all,       // [2560][512] fp32
    const float* __restrict__ s_all,       // [2560][512] fp32
    const u16* __restrict__ Wg_bf,         // [128pad][512] bf16
    const u16* __restrict__ Ws_bf,         // [128pad][512] bf16
    const u16* __restrict__ Vf_bf,         // [128*49][512] bf16
    const float* __restrict__ zbase,       // [128][49][49]
    const float* __restrict__ wh,          // [49]
    u16* __restrict__ Hc_bf,               // [2560][512] bf16
    float* __restrict__ attn_out)          // [128][20][49] fp32
{
    const int id = blockIdx.x, tid = threadIdx.x;
    const int xcd = id & 7, q = id >> 3;
    const int t = q % 20, b = xcd + 8*(q/20);
    const int r = t*128 + b;
    __shared__ float sH2[512], ss2[512];
    __shared__ float sgH[52], ssWs[52], swh[52], sz[52], salpha[52];

    for (int d = tid; d < 512; d += 256){
        sH2[d] = H_all[(size_t)r*512 + d];
        ss2[d] = s_all[(size_t)r*512 + d];
    }
    if (tid < 49) swh[tid] = wh[tid];
    __syncthreads();
    // gH[n] = H . Wg[n]  (lanes 0-48);  sWs[n] = s . Ws[n]  (lanes 64-112)
    if (tid < 49){
        const u16* wr = Wg_bf + (size_t)tid*512;
        float a = 0.f;
        for (int k = 0; k < 512; k += 8){
            uint4 v = *(const uint4*)(wr + k);
            a += bu2f(v.x&0xffff)*sH2[k]   + bu2f(v.x>>16)*sH2[k+1]
               + bu2f(v.y&0xffff)*sH2[k+2] + bu2f(v.y>>16)*sH2[k+3]
               + bu2f(v.z&0xffff)*sH2[k+4] + bu2f(v.z>>16)*sH2[k+5]
               + bu2f(v.w&0xffff)*sH2[k+6] + bu2f(v.w>>16)*sH2[k+7];
        }
        sgH[tid] = a;
    } else if (tid >= 64 && tid < 113){
        int n = tid - 64;
        const u16* wr = Ws_bf + (size_t)n*512;
        float a = 0.f;
        for (int k = 0; k < 512; k += 8){
            uint4 v = *(const uint4*)(wr + k);
            a += bu2f(v.x&0xffff)*ss2[k]   + bu2f(v.x>>16)*ss2[k+1]
               + bu2f(v.y&0xffff)*ss2[k+2] + bu2f(v.y>>16)*ss2[k+3]
               + bu2f(v.z&0xffff)*ss2[k+4] + bu2f(v.z>>16)*ss2[k+5]
               + bu2f(v.w&0xffff)*ss2[k+6] + bu2f(v.w>>16)*ss2[k+7];
        }
        ssWs[n] = a;
    }
    __syncthreads();
    if (tid < 49){
        const float* zb = zbase + (size_t)b*2401 + (size_t)tid*49;
        float a = 0.f;
        #pragma unroll
        for (int k = 0; k < 49; ++k) a += tanhf(zb[k] + sgH[k]) * swh[k];
        sz[tid] = a;
    } else if (tid == 64){
        float a = 0.f;
        #pragma unroll
        for (int k = 0; k < 49; ++k) a += tanhf(ssWs[k] + sgH[k]) * swh[k];
        sz[49] = a;
    }
    __syncthreads();
    if (tid < 64){
        float val = (tid < 50) ? sz[tid] : -1e30f;
        float mx = val;
        #pragma unroll
        for (int o = 32; o > 0; o >>= 1) mx = fmaxf(mx, __shfl_xor(mx, o));
        float e = (tid < 50) ? __expf(val - mx) : 0.f;
        float ssum = e;
        #pragma unroll
        for (int o = 32; o > 0; o >>= 1) ssum += __shfl_xor(ssum, o);
        float a = e/ssum;
        if (tid < 50) salpha[tid] = a;
        if (tid < 49) attn_out[((size_t)b*kT + t)*kN + tid] = a;
    }
    __syncthreads();
    for (int d = tid; d < 512; d += 256){
        float a = salpha[49] * ss2[d];
        const u16* vf = Vf_bf + (size_t)b*49*512 + d;
        #pragma unroll
        for (int n = 0; n < 49; ++n) a = fmaf(salpha[n], bu2f(vf[(size_t)n*512]), a);
        Hc_bf[(size_t)r*512 + d] = f2b(sH2[d] + a);
    }
}

// ================= log-softmax: read bf16 logits row (t*128+b), write fp32 row (b*20+t) =================
__global__ __launch_bounds__(256) void logsoftmax_k(const u16* __restrict__ logits_bf,
                                                    float* __restrict__ out0)
{
    const int r = blockIdx.x, tid = threadIdx.x;   // r = b*20+t
    const int b = r / 20, t = r - b*20;
    const u16* L = logits_bf + (size_t)(t*kB + b)*kV;
    __shared__ float rm[256], rs[256];
    float m = -1e30f, s = 0.f;
    for (int c = tid; c < kV/8; c += 256){
        uint4 v = *(const uint4*)(L + c*8);
        u32 w[4] = {v.x, v.y, v.z, v.w};
        #pragma unroll
        for (int j = 0; j < 4; ++j){
            float x0 = bu2f(w[j] & 0xffff), x1 = bu2f(w[j] >> 16);
            float nm = fmaxf(m, fmaxf(x0, x1));
            s = s*__expf(m - nm) + __expf(x0 - nm) + __expf(x1 - nm);
            m = nm;
        }
    }
    rm[tid] = m; rs[tid] = s; __syncthreads();
    for (int st = 128; st > 0; st >>= 1){
        if (tid < st){
            float m2 = rm[tid + st], s2 = rs[tid + st];
            float nm = fmaxf(rm[tid], m2);
            rs[tid] = rs[tid]*__expf(rm[tid] - nm) + s2*__expf(m2 - nm);
            rm[tid] = nm;
        }
        __syncthreads();
    }
    float lse = rm[0] + logf(rs[0]);
    float* D = out0 + (size_t)r*kV;
    for (int c = tid; c < kV/8; c += 256){
        uint4 v = *(const uint4*)(L + c*8);
        u32 w[4] = {v.x, v.y, v.z, v.w};
        f32x4v o0, o1;
        o0[0]=bu2f(w[0]&0xffff)-lse; o0[1]=bu2f(w[0]>>16)-lse;
        o0[2]=bu2f(w[1]&0xffff)-lse; o0[3]=bu2f(w[1]>>16)-lse;
        o1[0]=bu2f(w[2]&0xffff)-lse; o1[1]=bu2f(w[2]>>16)-lse;
        o1[2]=bu2f(w[3]&0xffff)-lse; o1[3]=bu2f(w[3]>>16)-lse;
        *(f32x4v*)(D + c*8) = o0;
        *(f32x4v*)(D + c*8 + 4) = o1;
    }
}

extern "C" void kernel_launch(void* const* d_in, const int* in_sizes, int n_in,
                              void* d_out, int out_size, void* d_ws, size_t ws_size,
                              hipStream_t stream)
{
    const float* img   = (const float*)d_in[0];
    const int*   target= (const int*)  d_in[1];
    const float* emb   = (const float*)d_in[2];
    const float* Wa    = (const float*)d_in[3];
    const float* ba    = (const float*)d_in[4];
    const float* Wb    = (const float*)d_in[5];
    const float* bb    = (const float*)d_in[6];
    const float* Whi   = (const float*)d_in[7];
    const float* bhi   = (const float*)d_in[8];
    const float* Wmi   = (const float*)d_in[9];
    const float* bmi   = (const float*)d_in[10];
    const float* Wih   = (const float*)d_in[11];
    const float* bih   = (const float*)d_in[12];
    const float* Whh   = (const float*)d_in[13];
    const float* bhh   = (const float*)d_in[14];
    const float* Wv    = (const float*)d_in[15];
    const float* Wg    = (const float*)d_in[16];
    const float* wh    = (const float*)d_in[17];
    const float* W_H   = (const float*)d_in[18];
    const float* Wx    = (const float*)d_in[19];
    const float* Wh2   = (const float*)d_in[20];
    const float* Wsm   = (const float*)d_in[21];
    const float* Wc    = (const float*)d_in[22];
    const float* bc    = (const float*)d_in[23];
    const float* Wfc   = (const float*)d_in[24];
    const float* bfc   = (const float*)d_in[25];
    const float* Wp    = (const float*)d_in[26];
    const float* bp    = (const float*)d_in[27];
    (void)in_sizes; (void)n_in; (void)out_size; (void)ws_size;

    float* out0 = (float*)d_out;                       // [B*T, V] logprobs (row b*20+t)
    float* attn_out = out0 + (size_t)kB*kT*kV;         // [B, T, N]

    char* base = (char*)d_ws;
    size_t off = 0;
    auto alloc = [&](size_t bytes)->char*{
        char* p = base + off;
        off += ((bytes + 255) & ~(size_t)255);
        return p;
    };
    // fixed region (W arrays padded to 128-row multiples for unchecked staging)
    u16* Wa_bf     = (u16*)alloc((size_t)kD*kC*2);
    u16* Winit_bf  = (u16*)alloc((size_t)1536*kC*2);
    u16* Wv_bf     = (u16*)alloc((size_t)128*kD*2);           // 49 -> 128 rows
    u16* Wp_bf     = (u16*)alloc((size_t)10112*kD*2);         // 10000 -> 10112 rows
    u16* Wfirst_bf = (u16*)alloc((size_t)2560*512*2); // [Wih[:, :512]; Wx[:, :512]]
    u16* Wlast_bf  = (u16*)alloc((size_t)2560*512*2); // [Wih[:, 512:]; Wx[:, 512:]]
    u8*  Wrec8     = (u8*)alloc((size_t)64*2048*8);           // fp8 il (Whh)
    float* rowscale = (float*)alloc(2048*4);
    u16* Wh2_bf    = (u16*)alloc((size_t)512*512*2);
    u16* WH_bf     = (u16*)alloc((size_t)512*512*2);
    u16* Wc_bf     = (u16*)alloc((size_t)512*512*2);
    u16* Wg_bf     = (u16*)alloc((size_t)128*512*2);          // 49 -> 128 rows
    u16* Ws_bf     = (u16*)alloc((size_t)128*512*2);          // 49 -> 128 rows
    u16* Wfc_bf    = (u16*)alloc((size_t)512*512*2);
    float* bias2560 = (float*)alloc(2560*4);
    float* bcat3    = (float*)alloc(1536*4);
    u16* meanb_bf   = (u16*)alloc((size_t)kB*kC*2);
    float* initC    = (float*)alloc((size_t)kB*1536*4);
    u16* init_bf    = (u16*)alloc((size_t)kB*1536*2);
    u16* Vf_bf      = (u16*)alloc((size_t)kB*kN*kD*2);
    float* zbase    = (float*)alloc((size_t)kB*kN*kN*4);
    u16* we_bf      = (u16*)alloc((size_t)kT*kB*kE*2);
    float* gbase    = (float*)alloc((size_t)kB*2560*4);
    u16* outbf      = (u16*)alloc((size_t)kT*kB*kD*2);
    u16* gtv_bf     = (u16*)alloc((size_t)kT*kB*kD*2);
    u16* hp_bf      = (u16*)alloc((size_t)(kT+1)*kB*kD*2);    // h sequence bf16 (h0..h20)
    u16* tm_bf      = (u16*)alloc((size_t)kT*kB*kD*2);        // tanh(m2) per step

    // dynamic region, time-multiplexed
    char* dyn = base + off;
    u16* img_bf    = (u16*)dyn;
    float* xall    = (float*)(dyn + (((size_t)kB*kN*kC*2 + 255) & ~(size_t)255));
    u16* logits_bf = (u16*)dyn;
    size_t poff = 0;
    auto palloc = [&](size_t bytes)->char*{
        char* p = dyn + poff;
        poff += ((bytes + 255) & ~(size_t)255);
        return p;
    };
    float* H_all   = (float*)palloc((size_t)kT*kB*kD*4);
    float* s_all   = (float*)palloc((size_t)kT*kB*kD*4);
    u16*   Hc_bf   = (u16*)  palloc((size_t)kT*kB*kD*2);
    // phase-2 buffers ~13MB < img_bf's 25.7MB: xall intact until gtv GEMM.

    auto G = [&](const u16* A, int lda, const u16* W, int ldw,
                 float* C, u16* Cbf, int ldc, int M, int N, int K,
                 const float* bias, const float* a1, int l1, int a1mask, int act,
                 const u16* mul2 = nullptr, int ldm = 0){
        dim3 g((N + TBN - 1)/TBN, (M + TBM - 1)/TBM);
        gemm_bf16<<<g, 256, 0, stream>>>(A, lda, W, ldw, C, Cbf, ldc, M, N, K,
                                         bias, a1, l1, a1mask, act, mul2, ldm, 0);
    };

    // ---- prep (5 launches) ----
    bias_prep_k<<<16, 256, 0, stream>>>(bih, bhh, bb, bhi, bmi, bias2560, bcat3);
    emb_gather_k<<<kT*kB*kE/256, 256, 0, stream>>>(target, emb, we_bf);
    img_cvt_mean_k<<<kB*kC/8/256, 256, 0, stream>>>(img, img_bf, meanb_bf);
    wrec8_prep_k<<<256, 512, 0, stream>>>(Whh, Wrec8, rowscale);
    {
        CvtTab tab{};
        int idx = 0, start = 0;
        auto add = [&](const float* src, void* dst, int src_ld, int Kshift, int rows){
            tab.d[idx] = {src, (unsigned long long)(size_t)dst, src_ld, Kshift, start};
            start += rows << Kshift; ++idx;
        };
        add(Wa,        Wa_bf,                        2048, 8, 512);
        add(Wb,        Winit_bf,                     2048, 8, 512);
        add(Whi,       Winit_bf + (size_t)512*kC,    2048, 8, 512);
        add(Wmi,       Winit_bf + (size_t)1024*kC,   2048, 8, 512);
        add(Wv,        Wv_bf,                         512, 6, 49);
        add(Wp,        Wp_bf,                         512, 6, 10000);
        add(Wih,       Wfirst_bf,                    1024, 6, 2048);
        add(Wx,        Wfirst_bf + (size_t)2048*512, 1024, 6, 512);
        add(Wih + 512, Wlast_bf,                     1024, 6, 2048);
        add(Wx  + 512, Wlast_bf + (size_t)2048*512,  1024, 6, 512);
        add(W_H,       WH_bf,                         512, 6, 512);
        add(Wc,        Wc_bf,                         512, 6, 512);
        add(Wg,        Wg_bf,                         512, 6, 49);
        add(Wsm,       Ws_bf,                         512, 6, 49);
        add(Wfc,       Wfc_bf,                        512, 6, 512);
        add(Wh2,       Wh2_bf,                        512, 6, 512);
        tab.total = start;
        int blocks = (start + 255)/256; if (blocks > 2048) blocks = 2048;
        multi_cvt_k<<<blocks, 256, 0, stream>>>(tab);
    }

    // ---- precompute GEMMs ----
    // [vg|h0|m0] = relu(mean @ [Wb;Whi;Wmi]^T + bcat3)
    G(meanb_bf, kC, Winit_bf, kC, initC, init_bf, 1536, kB, 1536, kC, bcat3, nullptr, 0, -1, 1);
    initcopy_k<<<kB*kD/256, 256, 0, stream>>>(initC, hp_bf);
    // Vf = relu(img @ Wa^T + ba)
    G(img_bf, kC, Wa_bf, kC, nullptr, Vf_bf, kD, kB*kN, kD, kC, ba, nullptr, 0, -1, 1);
    // zbase = Vf @ Wv^T
    G(Vf_bf, kD, Wv_bf, kD, zbase, nullptr, kN, kB*kN, kN, kD, nullptr, nullptr, 0, -1, 0);
    // gbase[b] = vg @ [Wih;Wx][:, :512]^T + [bih+bhh; 0]
    G(init_bf, 1536, Wfirst_bf, 512, gbase, nullptr, 2560, kB, 2560, kD, bias2560, nullptr, 0, -1, 0);
    // xall[t*128+b] = we @ [Wih;Wx][:, 512:]^T + gbase[b]
    G(we_bf, kE, Wlast_bf, 512, xall, nullptr, 2560, kT*kB, 2560, kE, nullptr, gbase, 2560, 127, 0);

    // ---- sequential LSTM recurrence: ONE launch (fp8 weights) ----
    scan_k<<<kB, 1024, 0, stream>>>(initC, xall, Wrec8, rowscale, hp_bf, tm_bf);

    // ---- deferred batched phases over M = T*B = 2560 rows ----
    // gtv = sigmoid(xall[:,2048:2560] + hprev @ Wh2^T) * tanh(m2)   (bf16)
    G(hp_bf, kD, Wh2_bf, kD, nullptr, gtv_bf, kD, kT*kB, kD, kD,
      nullptr, xall + 2048, 2560, 0x7fffffff, 3, tm_bf, kD);
    // H = relu(h2 @ WH^T)  (fp32 only)
    G(hp_bf + (size_t)kB*kD, kD, WH_bf, kD, H_all, nullptr, kD, kT*kB, kD, kD, nullptr, nullptr, 0, -1, 1);
    // s = relu(gtv @ Wc^T + bc)  (fp32 only)
    G(gtv_bf, kD, Wc_bf, kD, s_all, nullptr, kD, kT*kB, kD, kD, bc, nullptr, 0, -1, 1);
    // gH/sWs fused into attn_k; XCD-swizzled block order
    attn_k<<<kT*kB, 256, 0, stream>>>(H_all, s_all, Wg_bf, Ws_bf, Vf_bf, zbase, wh,
                                      Hc_bf, attn_out);
    // out = tanh(Hc @ Wfc^T + bfc)
    G(Hc_bf, kD, Wfc_bf, kD, nullptr, outbf, kD, kT*kB, kD, kD, bfc, nullptr, 0, -1, 2);

    // ---- logits (bf16, XCD-grouped swizzle) + log-softmax -> fp32 out ----
    {
        const int mblocks = (kT*kB + TBM - 1)/TBM;          // 20
        const int nblocks = (kV + TBN - 1)/TBN;             // 79
        const int groups  = (nblocks + 7)/8;                // 10
        dim3 g(groups*8*mblocks, 1);                        // 1600
        gemm_bf16<<<g, 256, 0, stream>>>(outbf, kD, Wp_bf, kD, nullptr, logits_bf, kV,
                                         kT*kB, kV, kD, bp, nullptr, 0, -1, 0, nullptr, 0, 1);
    }
    logsoftmax_k<<<kB*kT, 256, 0, stream>>>(logits_bf, out0);
}